// Round 7
// baseline (123.698 us; speedup 1.0000x reference)
//
#include <hip/hip_runtime.h>
#include <stdint.h>

// BiaffineSpanHead: B=4, S=1024, IN=1024, H=256, C=8
// out[b,s,e,c] = sum_{h,g} Hs[b,s,h] U[h,c,g] He[b,e,g] + linS[b,s,c] + linE[b,e,c] + Wb[c]
//
// R7: K2 fused into K3 ("k23"): each block owns a 16-s-row band of one batch.
//  phase1: T-band[128 m][256 g] = Hs-band @ Ut^T  (MFMA, A from global Ut,
//          B-frags in regs, acc -> bf16 -> swizzled LDS; no recompute: 4.3 GF total)
//  phase2: Out-band = T-band(LDS) @ He^T + lin    (17.2 GF; A has zero staging,
//          only He streams 16KB/kt; write-bound, stores overlap via TLP)
// Chain: prep -> K1 -> lin -> k23.  Tbf eliminated (16MB write + L2 re-reads).

#define BDIM 256

typedef float f32x4 __attribute__((ext_vector_type(4)));
typedef __bf16 bf16x8 __attribute__((ext_vector_type(8)));
typedef unsigned int u32;
typedef unsigned short u16;
typedef const __attribute__((address_space(1))) u32* gas_ptr;
typedef __attribute__((address_space(3))) u32* las_ptr;

static __device__ __forceinline__ void load_lds16(const void* g, void* l) {
  __builtin_amdgcn_global_load_lds((gas_ptr)g, (las_ptr)l, 16, 0, 0);
}

static __device__ __forceinline__ u16 f32_to_bf16(float f) {
  union { float f; u32 u; } v; v.f = f;
  u32 r = v.u + 0x7FFFu + ((v.u >> 16) & 1u);
  return (u16)(r >> 16);
}
static __device__ __forceinline__ float bf16lo_to_f32(u32 u) {
  union { u32 u; float f; } v; v.u = u << 16;
  return v.f;
}
static __device__ __forceinline__ float bf16hi_to_f32(u32 u) {
  union { u32 u; float f; } v; v.u = u & 0xFFFF0000u;
  return v.f;
}

// read an 8-elem bf16 fragment from a swizzled 64-col row:
// layout addr(m,g) = base + m*64 + (((g>>3 & 7) ^ (m & 7)) << 3) + (g & 7)
static __device__ __forceinline__ bf16x8 rd64(const u16* lds, int base, int row, int kslot) {
  return *reinterpret_cast<const bf16x8*>(&lds[base + row * 64 + ((kslot ^ (row & 7)) << 3)]);
}

// ---------------------------------------------------------------------------
// k23: 256 blocks x 512 threads (8 waves), 80KB dynamic LDS, 1 block/CU.
//  LDS: [0, 32768) u16  : T-band, 4 stripes of [128 m][64 g] swizzled
//       [32768, 40960)  : He stripe [128 e][64 g] swizzled (single buffer)
// ---------------------------------------------------------------------------
__global__ __launch_bounds__(512, 2)
void k23(const u16* __restrict__ Hboth,   // [4096][512] (Hs | He)
         const u16* __restrict__ Utbf,    // [2048][256]
         float* __restrict__ Out,         // [4][1024][1024][8]
         const float* __restrict__ linSall,
         const float* __restrict__ linEall)
{
  extern __shared__ u16 lds[];

  const int tid  = threadIdx.x;       // 0..511
  const int lane = tid & 63;
  const int wv   = tid >> 6;          // 0..7
  const int rA   = lane & 15;
  const int kq   = lane >> 4;         // 0..3

  // XCD swizzle: consecutive blocks on one XCD share z (He/Ut L2 locality)
  int id = (blockIdx.x & 7) * 32 + (blockIdx.x >> 3);   // bijective, 256 blocks
  const int z  = id >> 6;             // 0..3
  const int s0 = (id & 63) * 16;      // band start (s)

  const u16* HsZ = Hboth + ((size_t)(z * 1024 + s0)) * 512;       // Hs cols 0..255
  const u16* HeZ = Hboth + ((size_t)(z * 1024)) * 512 + 256;      // He cols

  // ======== phase 1: T-band = Hs-band @ Ut^T ========
  // P[cg, s] = sum_h Ut[cg,h] * Hs[s,h];  wave wv owns cg in [wv*256, wv*256+256)
  // => c == wv, g = t*16 + kq*4 + r, m = rA*8 + wv (s = rA local)
  bf16x8 bq[8];
#pragma unroll
  for (int ks = 0; ks < 8; ++ks)
    bq[ks] = *reinterpret_cast<const bf16x8*>(HsZ + (size_t)rA * 512 + ks * 32 + kq * 8);

  f32x4 p[16];
#pragma unroll
  for (int t = 0; t < 16; ++t) p[t] = (f32x4)0.f;

  const u16* UtW = Utbf + ((size_t)(wv * 256 + rA)) * 256 + kq * 8;
#pragma unroll
  for (int ks = 0; ks < 8; ++ks) {
#pragma unroll
    for (int t = 0; t < 16; ++t) {
      const bf16x8 a = *reinterpret_cast<const bf16x8*>(UtW + t * 16 * 256 + ks * 32);
      p[t] = __builtin_amdgcn_mfma_f32_16x16x32_bf16(a, bq[ks], p[t], 0, 0, 0);
    }
  }

  // write T-band to LDS in the rd64 layout (one ds_write_b64 per tile)
  {
    const int m = rA * 8 + wv;          // m & 7 == wv
    const int mbase = m * 64;
#pragma unroll
    for (int t = 0; t < 16; ++t) {
      ushort4 w4;
      w4.x = f32_to_bf16(p[t][0]);
      w4.y = f32_to_bf16(p[t][1]);
      w4.z = f32_to_bf16(p[t][2]);
      w4.w = f32_to_bf16(p[t][3]);
      const int kslot = (t & 3) * 2 + (kq >> 1);          // (g>>3) & 7
      const int addr = (t >> 2) * 8192 + mbase + ((kslot ^ wv) << 3) + (kq & 1) * 4;
      *reinterpret_cast<ushort4*>(&lds[addr]) = w4;
    }
  }
  __syncthreads();

  // ======== phase 2: Out-band = T-band @ He^T + lin ========
  const int wr = wv >> 2;   // 0..1  (64-row halves of the 128-row band)
  const int wc = wv & 3;    // 0..3  (32-col quarters of the 128-e tile)

  float* OutZ = Out + (size_t)z * 8388608;
  const float* lS = linSall + ((size_t)(z * 1024 + s0)) * 8;   // 128 floats, band-local
  const float* lE = linEall + (size_t)z * 8192;

  float4 ls4[4];
#pragma unroll
  for (int mi = 0; mi < 4; ++mi)
    ls4[mi] = *reinterpret_cast<const float4*>(lS + wr * 64 + mi * 16 + kq * 4);

#pragma unroll 1
  for (int nt = 0; nt < 8; ++nt) {
    const int e0 = nt * 128;
    f32x4 acc[4][2];
#pragma unroll
    for (int i = 0; i < 4; ++i)
#pragma unroll
      for (int j = 0; j < 2; ++j) acc[i][j] = (f32x4)0.f;

#pragma unroll 1
    for (int kt = 0; kt < 4; ++kt) {
      // stage He stripe [128 e][64 g] with pre-swizzled source (rule #21)
#pragma unroll
      for (int hh = 0; hh < 2; ++hh) {
        const int idx = hh * 512 + tid;
        const int r = idx >> 3;
        const int sl = idx & 7;
        load_lds16(HeZ + (size_t)(e0 + r) * 512 + kt * 64 + ((sl ^ (r & 7)) << 3),
                   &lds[32768 + idx * 8]);
      }
      __syncthreads();

      bf16x8 aF[4][2], bF[2][2];
#pragma unroll
      for (int mi = 0; mi < 4; ++mi)
#pragma unroll
        for (int ks = 0; ks < 2; ++ks)
          aF[mi][ks] = rd64(lds, kt * 8192, wr * 64 + mi * 16 + rA, (ks << 2) | kq);
#pragma unroll
      for (int ni = 0; ni < 2; ++ni)
#pragma unroll
        for (int ks = 0; ks < 2; ++ks)
          bF[ni][ks] = rd64(lds, 32768, wc * 32 + ni * 16 + rA, (ks << 2) | kq);
#pragma unroll
      for (int mi = 0; mi < 4; ++mi)
#pragma unroll
        for (int ni = 0; ni < 2; ++ni)
#pragma unroll
          for (int ks = 0; ks < 2; ++ks)
            acc[mi][ni] = __builtin_amdgcn_mfma_f32_16x16x32_bf16(
                aF[mi][ks], bF[ni][ks], acc[mi][ni], 0, 0, 0);
      __syncthreads();
    }

    // epilogue for this n-tile: float4 stores, lin fused
#pragma unroll
    for (int mi = 0; mi < 4; ++mi) {
      const int mBase = wr * 64 + mi * 16 + kq * 4;   // band m = s_local*8 + c0
      const int s = mBase >> 3;
      const int c0 = mBase & 7;
#pragma unroll
      for (int ni = 0; ni < 2; ++ni) {
        const int e = e0 + wc * 32 + ni * 16 + rA;
        const float4 le4 = *reinterpret_cast<const float4*>(lE + e * 8 + c0);
        float4 o;
        o.x = acc[mi][ni][0] + ls4[mi].x + le4.x;
        o.y = acc[mi][ni][1] + ls4[mi].y + le4.y;
        o.z = acc[mi][ni][2] + ls4[mi].z + le4.z;
        o.w = acc[mi][ni][3] + ls4[mi].w + le4.w;
        *reinterpret_cast<float4*>(OutZ + (((size_t)(s0 + s)) << 13) + ((size_t)e << 3) + c0) = o;
      }
    }
  }
}

// ---------------------------------------------------------------------------
// K1: 2-phase 128-wide B^T GEMM (R4/R6-proven), bf16 out + dual bias.
// ---------------------------------------------------------------------------
template <int IM, int EPI>
__global__ __launch_bounds__(BDIM, 2)
void gemm_bt(const u16* __restrict__ Aall,
             const u16* __restrict__ Ball,
             void* __restrict__ OutAll,
             const int N, const int K, const int lda, const int ldb,
             const float* __restrict__ bias0,
             const float* __restrict__ bias1)
{
  constexpr int WM = IM * 16;
  constexpr int TM = 2 * WM;

  __shared__ u16 lsA[TM * 32];
  __shared__ u16 lsB[128 * 32];

  const int tid  = threadIdx.x;
  const int lane = tid & 63;
  const int wv   = tid >> 6;
  const int wr   = wv >> 1;
  const int wc   = wv & 1;

  const int gx = gridDim.x;
  const int nwg = gx * gridDim.y;
  int id = blockIdx.y * gx + blockIdx.x;
  {
    const int q = nwg >> 3;
    id = (id & 7) * q + (id >> 3);
  }
  const int n0 = (id % gx) * 128;
  const int m0 = (id / gx) * TM;

  const u16* A  = Aall;
  const u16* Bm = Ball;

  f32x4 acc[IM][4];
#pragma unroll
  for (int i = 0; i < IM; ++i)
#pragma unroll
    for (int j = 0; j < 4; ++j) acc[i][j] = (f32x4)0.f;

  const int rA = lane & 15;
  const int ko = (lane >> 4) * 8;

  for (int kt = 0; kt < K; kt += 32) {
    constexpr int CA = TM * 4;
#pragma unroll
    for (int it = 0; it < CA / BDIM; ++it) {
      const int chunk = it * BDIM + tid;
      const int row = chunk >> 2;
      const int ce = (chunk & 3) * 8;
      load_lds16(A + (size_t)(m0 + row) * lda + (kt + ce), &lsA[chunk * 8]);
    }
#pragma unroll
    for (int it = 0; it < 2; ++it) {
      const int chunk = it * BDIM + tid;
      const int row = chunk >> 2;
      const int ce = (chunk & 3) * 8;
      load_lds16(Bm + (size_t)(n0 + row) * ldb + (kt + ce), &lsB[chunk * 8]);
    }
    __syncthreads();

    bf16x8 aF[IM], bF[4];
#pragma unroll
    for (int i = 0; i < IM; ++i)
      aF[i] = *reinterpret_cast<const bf16x8*>(&lsA[(wr * WM + i * 16 + rA) * 32 + ko]);
#pragma unroll
    for (int j = 0; j < 4; ++j)
      bF[j] = *reinterpret_cast<const bf16x8*>(&lsB[(wc * 64 + j * 16 + rA) * 32 + ko]);
#pragma unroll
    for (int i = 0; i < IM; ++i)
#pragma unroll
      for (int j = 0; j < 4; ++j)
        acc[i][j] = __builtin_amdgcn_mfma_f32_16x16x32_bf16(aF[i], bF[j], acc[i][j], 0, 0, 0);
    __syncthreads();
  }

  const int rgr = (lane >> 4) * 4;
  u16* Out = (u16*)OutAll;
#pragma unroll
  for (int i = 0; i < IM; ++i) {
#pragma unroll
    for (int j = 0; j < 4; ++j) {
      const int mBase = m0 + wr * WM + i * 16 + rgr;
      const int n = n0 + wc * 64 + j * 16 + rA;
      float bn = 0.f;
      if constexpr (EPI == 1) bn = (n < 256) ? bias0[n] : bias1[n - 256];
#pragma unroll
      for (int r = 0; r < 4; ++r) {
        Out[(size_t)(mBase + r) * N + n] = f32_to_bf16(acc[i][j][r] + bn);
      }
    }
  }
}

// ---------------------------------------------------------------------------
// lin: linS[m,c] = Hs[m]·Ws[c] ; linE[m,c] = He[m]·We[c] + Wb[c]
// ---------------------------------------------------------------------------
__global__ __launch_bounds__(BDIM)
void lin_kernel(const u16* __restrict__ Hboth,
                const float* __restrict__ Ww,
                const float* __restrict__ Wb,
                float* __restrict__ linS,
                float* __restrict__ linE)
{
  const int idx = blockIdx.x * BDIM + threadIdx.x;   // 0..32767
  const int m = idx >> 3;
  const int c = idx & 7;
  const uint4* hs4 = reinterpret_cast<const uint4*>(Hboth + (size_t)m * 512);
  const uint4* he4 = reinterpret_cast<const uint4*>(Hboth + (size_t)m * 512 + 256);
  const float* wsp = Ww + c * 512;
  const float* wep = wsp + 256;
  float s1 = 0.f, s2 = 0.f;
#pragma unroll 4
  for (int t = 0; t < 32; ++t) {
    const uint4 a = hs4[t];
    const uint4 b = he4[t];
    const u32 aw[4] = {a.x, a.y, a.z, a.w};
    const u32 bw[4] = {b.x, b.y, b.z, b.w};
#pragma unroll
    for (int q = 0; q < 4; ++q) {
      const int h = t * 8 + q * 2;
      s1 += bf16lo_to_f32(aw[q]) * wsp[h] + bf16hi_to_f32(aw[q]) * wsp[h + 1];
      s2 += bf16lo_to_f32(bw[q]) * wep[h] + bf16hi_to_f32(bw[q]) * wep[h + 1];
    }
  }
  linS[idx] = s1;
  linE[idx] = s2 + Wb[c];
}

// ---------------------------------------------------------------------------
__global__ void prep_kernel(const float* __restrict__ seq,
                            const float* __restrict__ sw,
                            const float* __restrict__ ew,
                            const float* __restrict__ U,
                            u16* __restrict__ Xbf,
                            u16* __restrict__ wbf,
                            u16* __restrict__ Ut)
{
  const int bid = blockIdx.x;
  const int tid = threadIdx.x;
  if (bid < 4096) {
    const int i = bid * 1024 + tid * 4;
    const float4 v = *reinterpret_cast<const float4*>(seq + i);
    ushort4 o;
    o.x = f32_to_bf16(v.x); o.y = f32_to_bf16(v.y);
    o.z = f32_to_bf16(v.z); o.w = f32_to_bf16(v.w);
    *reinterpret_cast<ushort4*>(Xbf + i) = o;
  } else if (bid < 4608) {
    const int i = (bid - 4096) * 1024 + tid * 4;
    const float* src = (i < 262144) ? (sw + i) : (ew + (i - 262144));
    const float4 v = *reinterpret_cast<const float4*>(src);
    ushort4 o;
    o.x = f32_to_bf16(v.x); o.y = f32_to_bf16(v.y);
    o.z = f32_to_bf16(v.z); o.w = f32_to_bf16(v.w);
    *reinterpret_cast<ushort4*>(wbf + i) = o;
  } else {
    const int i = (bid - 4608) * 1024 + tid * 4;  // i = n*256 + h
    const int n = i >> 8;
    const int h = i & 255;
    ushort4 o;
    o.x = f32_to_bf16(U[(size_t)(h + 0) * 2048 + n]);
    o.y = f32_to_bf16(U[(size_t)(h + 1) * 2048 + n]);
    o.z = f32_to_bf16(U[(size_t)(h + 2) * 2048 + n]);
    o.w = f32_to_bf16(U[(size_t)(h + 3) * 2048 + n]);
    *reinterpret_cast<ushort4*>(Ut + i) = o;
  }
}

// ---------------------------------------------------------------------------
extern "C" void kernel_launch(void* const* d_in, const int* in_sizes, int n_in,
                              void* d_out, int out_size, void* d_ws, size_t ws_size,
                              hipStream_t stream)
{
  const float* seq = (const float*)d_in[0];
  const float* U   = (const float*)d_in[1];
  const float* Ww  = (const float*)d_in[2];
  const float* Wb  = (const float*)d_in[3];
  const float* sw  = (const float*)d_in[4];
  const float* sb  = (const float*)d_in[5];
  const float* ew  = (const float*)d_in[6];
  const float* eb  = (const float*)d_in[7];
  float* out = (float*)d_out;

  u16* Xbf   = (u16*)d_ws;                 // 4194304
  u16* wbf   = Xbf  + 4194304;             // 524288  [512][1024]
  u16* Utbf  = wbf  + 524288;              // 524288  [2048][256]
  u16* Hboth = Utbf + 524288;              // 2097152 [4096][512]
  float* linS = (float*)(Hboth + 2097152); // 32768
  float* linE = linS + 32768;              // 32768

  prep_kernel<<<5120, BDIM, 0, stream>>>(seq, sw, ew, U, Xbf, wbf, Utbf);

  // K1: Hboth = X @ [sw;ew]^T + [sb;eb]  (M=4096, N=512, K=1024)
  gemm_bt<2, 1><<<dim3(4, 64, 1), BDIM, 0, stream>>>(
      Xbf, wbf, Hboth, 512, 1024, 1024, 1024, sb, eb);

  lin_kernel<<<128, BDIM, 0, stream>>>(Hboth, Ww, Wb, linS, linE);

  // k23: fused T-band + biaff  (256 blocks, 80KB dynamic LDS)
  hipFuncSetAttribute(reinterpret_cast<const void*>(&k23),
                      hipFuncAttributeMaxDynamicSharedMemorySize, 81920);
  k23<<<256, 512, 81920, stream>>>(Hboth, Utbf, out, linS, linE);
}

// Round 8
// 85.192 us; speedup vs baseline: 1.4520x; 1.4520x over previous
//
#include <hip/hip_runtime.h>
#include <stdint.h>

// BiaffineSpanHead: B=4, S=1024, IN=1024, H=256, C=8
// out[b,s,e,c] = sum_{h,g} Hs[b,s,h] U[h,c,g] He[b,e,g] + linS[b,s,c] + linE[b,e,c] + Wb[c]
//
// R8: revert R7's k23 (1 block/CU fusion disease, 2nd confirmation). R6 chain
// with K1 re-tiled: 64x64, BK=64, grid 512 (2-4 blocks/CU, 16 waves/CU) --
// K1 previously ran 256 blocks = 1 block/CU, 4 waves/CU (latency-dominated).

#define BDIM 256

typedef float f32x4 __attribute__((ext_vector_type(4)));
typedef __bf16 bf16x8 __attribute__((ext_vector_type(8)));
typedef unsigned int u32;
typedef unsigned short u16;
typedef const __attribute__((address_space(1))) u32* gas_ptr;
typedef __attribute__((address_space(3))) u32* las_ptr;

static __device__ __forceinline__ void load_lds16(const void* g, void* l) {
  __builtin_amdgcn_global_load_lds((gas_ptr)g, (las_ptr)l, 16, 0, 0);
}

static __device__ __forceinline__ u16 f32_to_bf16(float f) {
  union { float f; u32 u; } v; v.f = f;
  u32 r = v.u + 0x7FFFu + ((v.u >> 16) & 1u);
  return (u16)(r >> 16);
}
static __device__ __forceinline__ float bf16lo_to_f32(u32 u) {
  union { u32 u; float f; } v; v.u = u << 16;
  return v.f;
}
static __device__ __forceinline__ float bf16hi_to_f32(u32 u) {
  union { u32 u; float f; } v; v.u = u & 0xFFFF0000u;
  return v.f;
}

// stage a 32-row x 64-col bf16 stripe with 256 threads; LDS slot sl of row r
// holds global k-group sl ^ (r&7)  (T2 swizzle via pre-swizzled source).
static __device__ __forceinline__ void stage32(u16* lds, int dst, const u16* src,
                                               int srow, int ld, int kcol, int tid) {
  const int r = tid >> 3;        // 0..31
  const int sl = tid & 7;
  load_lds16(src + (size_t)(srow + r) * ld + kcol + ((sl ^ (r & 7)) << 3),
             &lds[dst + tid * 8]);
}

// read an 8-elem bf16 fragment from a swizzled 64-col row
static __device__ __forceinline__ bf16x8 rd64(const u16* lds, int base, int row, int kslot) {
  return *reinterpret_cast<const bf16x8*>(&lds[base + row * 64 + ((kslot ^ (row & 7)) << 3)]);
}

// ---------------------------------------------------------------------------
// K1: Hboth = X @ [sw;ew]^T + bias.  64x64 tile, BK=64, 4 waves (2x2),
// grid (8 n, 64 m) = 512 blocks -> 2-4 blocks/CU.
// ---------------------------------------------------------------------------
__global__ __launch_bounds__(BDIM, 4)
void k1(const u16* __restrict__ Xbf,     // [4096][1024]
        const u16* __restrict__ wbf,     // [512][1024]
        u16* __restrict__ Hboth,         // [4096][512]
        const float* __restrict__ sb,
        const float* __restrict__ eb)
{
  __shared__ u16 lds[2 * 4096];   // A [64][64] @0, B [64][64] @4096

  const int tid  = threadIdx.x;
  const int lane = tid & 63;
  const int wv   = tid >> 6;     // 0..3
  const int wr   = wv >> 1;      // 0..1 (32-row half)
  const int wq   = wv & 1;       // 0..1 (32-col half)
  const int rA   = lane & 15;
  const int kq   = lane >> 4;    // 0..3

  int id = blockIdx.y * gridDim.x + blockIdx.x;     // 0..511
  id = (id & 7) * 64 + (id >> 3);                   // bijective XCD swizzle
  const int n0 = (id & 7) * 64;
  const int m0 = (id >> 3) * 64;

  f32x4 acc[2][2];
#pragma unroll
  for (int i = 0; i < 2; ++i)
#pragma unroll
    for (int j = 0; j < 2; ++j) acc[i][j] = (f32x4)0.f;

#pragma unroll 1
  for (int kt = 0; kt < 1024; kt += 64) {
    stage32(lds, 0,        Xbf, m0,      1024, kt, tid);
    stage32(lds, 2048,     Xbf, m0 + 32, 1024, kt, tid);
    stage32(lds, 4096,     wbf, n0,      1024, kt, tid);
    stage32(lds, 4096+2048,wbf, n0 + 32, 1024, kt, tid);
    __syncthreads();

    bf16x8 aF[2][2], bF[2][2];
#pragma unroll
    for (int mi = 0; mi < 2; ++mi)
#pragma unroll
      for (int ks = 0; ks < 2; ++ks)
        aF[mi][ks] = rd64(lds, 0, wr * 32 + mi * 16 + rA, (ks << 2) | kq);
#pragma unroll
    for (int ni = 0; ni < 2; ++ni)
#pragma unroll
      for (int ks = 0; ks < 2; ++ks)
        bF[ni][ks] = rd64(lds, 4096, wq * 32 + ni * 16 + rA, (ks << 2) | kq);
#pragma unroll
    for (int mi = 0; mi < 2; ++mi)
#pragma unroll
      for (int ni = 0; ni < 2; ++ni)
#pragma unroll
        for (int ks = 0; ks < 2; ++ks)
          acc[mi][ni] = __builtin_amdgcn_mfma_f32_16x16x32_bf16(
              aF[mi][ks], bF[ni][ks], acc[mi][ni], 0, 0, 0);
    __syncthreads();
  }

  // epilogue: C/D col=lane&15, row=kq*4+r
#pragma unroll
  for (int mi = 0; mi < 2; ++mi) {
#pragma unroll
    for (int ni = 0; ni < 2; ++ni) {
      const int n = n0 + wq * 32 + ni * 16 + rA;
      const float bn = (n < 256) ? sb[n] : eb[n - 256];
      const int mr = m0 + wr * 32 + mi * 16 + kq * 4;
#pragma unroll
      for (int r = 0; r < 4; ++r)
        Hboth[(size_t)(mr + r) * 512 + n] = f32_to_bf16(acc[mi][ni][r] + bn);
    }
  }
}

// ---------------------------------------------------------------------------
// K3: 128x128 tile, BK=64, 256 threads (4 waves 2x2), single-buffer 2-phase.
// (R6-proven, verbatim)
// ---------------------------------------------------------------------------
__global__ __launch_bounds__(BDIM, 4)
void gemm128_biaff(const u16* __restrict__ Tall,
                   const u16* __restrict__ Bg,
                   float* __restrict__ Out,
                   const float* __restrict__ linSall,
                   const float* __restrict__ linEall)
{
  __shared__ u16 lds[2 * 8192];    // lsA at 0, lsB at 8192 (u16 units)

  const int tid  = threadIdx.x;
  const int lane = tid & 63;
  const int wv   = tid >> 6;       // 0..3
  const int wr   = wv >> 1;        // 0..1
  const int wc   = wv & 1;         // 0..1
  const int rA   = lane & 15;
  const int kq   = lane >> 4;      // 0..3
  const int z    = blockIdx.z;

  int id = blockIdx.y * gridDim.x + blockIdx.x;
  id = (id & 7) * 64 + (id >> 3);
  const int n0 = (id & 7) * 128;
  const int m0 = (id >> 3) * 128;

  const u16* Ag  = Tall + (size_t)z * (8192 * 256);
  const u16* Bgz = Bg   + (size_t)z * (1024 * 512);

  f32x4 acc[4][4];
#pragma unroll
  for (int i = 0; i < 4; ++i)
#pragma unroll
    for (int j = 0; j < 4; ++j) acc[i][j] = (f32x4)0.f;

#pragma unroll 1
  for (int kt = 0; kt < 256; kt += 64) {
#pragma unroll
    for (int h = 0; h < 4; ++h)
      stage32(lds, h * 2048, Ag, m0 + h * 32, 256, kt, tid);
#pragma unroll
    for (int h = 0; h < 4; ++h)
      stage32(lds, 8192 + h * 2048, Bgz, n0 + h * 32, 512, kt, tid);
    __syncthreads();

    bf16x8 aF[4][2], bF[4][2];
#pragma unroll
    for (int mi = 0; mi < 4; ++mi)
#pragma unroll
      for (int ks = 0; ks < 2; ++ks)
        aF[mi][ks] = rd64(lds, 0, wr * 64 + mi * 16 + rA, (ks << 2) | kq);
#pragma unroll
    for (int ni = 0; ni < 4; ++ni)
#pragma unroll
      for (int ks = 0; ks < 2; ++ks)
        bF[ni][ks] = rd64(lds, 8192, wc * 64 + ni * 16 + rA, (ks << 2) | kq);
#pragma unroll
    for (int mi = 0; mi < 4; ++mi)
#pragma unroll
      for (int ni = 0; ni < 4; ++ni)
#pragma unroll
        for (int ks = 0; ks < 2; ++ks)
          acc[mi][ni] = __builtin_amdgcn_mfma_f32_16x16x32_bf16(
              aF[mi][ks], bF[ni][ks], acc[mi][ni], 0, 0, 0);
    __syncthreads();
  }

  float* OutZ = Out + (size_t)z * 8388608;
  const float* lS = linSall + (size_t)z * 8192;
  const float* lE = linEall + (size_t)z * 8192;
#pragma unroll
  for (int mi = 0; mi < 4; ++mi) {
#pragma unroll
    for (int ni = 0; ni < 4; ++ni) {
      const int mBase = m0 + wr * 64 + mi * 16 + kq * 4;   // = s*8 + c0
      const int e = n0 + wc * 64 + ni * 16 + rA;
      const int s = mBase >> 3;
      const int c0 = mBase & 7;
      const float4 ls4 = *reinterpret_cast<const float4*>(lS + mBase);
      const float4 le4 = *reinterpret_cast<const float4*>(lE + (e << 3) + c0);
      float4 o;
      o.x = acc[mi][ni][0] + ls4.x + le4.x;
      o.y = acc[mi][ni][1] + ls4.y + le4.y;
      o.z = acc[mi][ni][2] + ls4.z + le4.z;
      o.w = acc[mi][ni][3] + ls4.w + le4.w;
      *reinterpret_cast<float4*>(OutZ + ((size_t)s << 13) + ((size_t)e << 3) + c0) = o;
    }
  }
}

// ---------------------------------------------------------------------------
// K2 + lin fused (R6-proven, verbatim): blocks 0..511 = K2 tiles, 512..639 lin
// ---------------------------------------------------------------------------
__global__ __launch_bounds__(BDIM, 2)
void k2lin(const u16* __restrict__ Hboth,
           const u16* __restrict__ Utbf,
           u16* __restrict__ Tbf,
           const float* __restrict__ Ww,
           const float* __restrict__ Wb,
           float* __restrict__ linS,
           float* __restrict__ linE)
{
  const int bid = blockIdx.x;
  const int tid = threadIdx.x;

  if (bid >= 512) {
    const int idx = (bid - 512) * BDIM + tid;   // 0..32767
    const int m = idx >> 3;
    const int c = idx & 7;
    const uint4* hs4 = reinterpret_cast<const uint4*>(Hboth + (size_t)m * 512);
    const uint4* he4 = reinterpret_cast<const uint4*>(Hboth + (size_t)m * 512 + 256);
    const float* wsp = Ww + c * 512;
    const float* wep = wsp + 256;
    float s1 = 0.f, s2 = 0.f;
#pragma unroll 4
    for (int t = 0; t < 32; ++t) {
      const uint4 a = hs4[t];
      const uint4 b = he4[t];
      const u32 aw[4] = {a.x, a.y, a.z, a.w};
      const u32 bw[4] = {b.x, b.y, b.z, b.w};
#pragma unroll
      for (int q = 0; q < 4; ++q) {
        const int h = t * 8 + q * 2;
        s1 += bf16lo_to_f32(aw[q]) * wsp[h] + bf16hi_to_f32(aw[q]) * wsp[h + 1];
        s2 += bf16lo_to_f32(bw[q]) * wep[h] + bf16hi_to_f32(bw[q]) * wep[h + 1];
      }
    }
    linS[idx] = s1;
    linE[idx] = s2 + Wb[c];
    return;
  }

  __shared__ u16 lsA[128 * 32];
  __shared__ u16 lsB[128 * 32];

  int id = bid;
  id = (id & 7) * 64 + (id >> 3);
  const int n0 = (id & 15) * 128;
  const int m0 = (id >> 4) * 128;

  const int lane = tid & 63;
  const int wv   = tid >> 6;
  const int wr   = wv >> 1;
  const int wc   = wv & 1;
  const int rA   = lane & 15;
  const int ko   = (lane >> 4) * 8;

  f32x4 acc[4][4];
#pragma unroll
  for (int i = 0; i < 4; ++i)
#pragma unroll
    for (int j = 0; j < 4; ++j) acc[i][j] = (f32x4)0.f;

  for (int kt = 0; kt < 256; kt += 32) {
#pragma unroll
    for (int it = 0; it < 2; ++it) {
      const int chunk = it * BDIM + tid;
      const int row = chunk >> 2;
      const int ce = (chunk & 3) * 8;
      load_lds16(Hboth + (size_t)(m0 + row) * 512 + (kt + ce), &lsA[chunk * 8]);
      load_lds16(Utbf + (size_t)(n0 + row) * 256 + (kt + ce), &lsB[chunk * 8]);
    }
    __syncthreads();

    bf16x8 aF[4], bF[4];
#pragma unroll
    for (int i = 0; i < 4; ++i)
      aF[i] = *reinterpret_cast<const bf16x8*>(&lsA[(wr * 64 + i * 16 + rA) * 32 + ko]);
#pragma unroll
    for (int j = 0; j < 4; ++j)
      bF[j] = *reinterpret_cast<const bf16x8*>(&lsB[(wc * 64 + j * 16 + rA) * 32 + ko]);
#pragma unroll
    for (int i = 0; i < 4; ++i)
#pragma unroll
      for (int j = 0; j < 4; ++j)
        acc[i][j] = __builtin_amdgcn_mfma_f32_16x16x32_bf16(aF[i], bF[j], acc[i][j], 0, 0, 0);
    __syncthreads();
  }

  const int rgr = (lane >> 4) * 4;
#pragma unroll
  for (int i = 0; i < 4; ++i) {
#pragma unroll
    for (int j = 0; j < 4; ++j) {
      const int mBase = m0 + wr * 64 + i * 16 + rgr;
      const int n = n0 + wc * 64 + j * 16 + rA;
#pragma unroll
      for (int r = 0; r < 4; ++r)
        Tbf[(size_t)(mBase + r) * 2048 + n] = f32_to_bf16(acc[i][j][r]);
    }
  }
}

// ---------------------------------------------------------------------------
__global__ void prep_kernel(const float* __restrict__ seq,
                            const float* __restrict__ sw,
                            const float* __restrict__ ew,
                            const float* __restrict__ U,
                            u16* __restrict__ Xbf,
                            u16* __restrict__ wbf,
                            u16* __restrict__ Ut)
{
  const int bid = blockIdx.x;
  const int tid = threadIdx.x;
  if (bid < 4096) {
    const int i = bid * 1024 + tid * 4;
    const float4 v = *reinterpret_cast<const float4*>(seq + i);
    ushort4 o;
    o.x = f32_to_bf16(v.x); o.y = f32_to_bf16(v.y);
    o.z = f32_to_bf16(v.z); o.w = f32_to_bf16(v.w);
    *reinterpret_cast<ushort4*>(Xbf + i) = o;
  } else if (bid < 4608) {
    const int i = (bid - 4096) * 1024 + tid * 4;
    const float* src = (i < 262144) ? (sw + i) : (ew + (i - 262144));
    const float4 v = *reinterpret_cast<const float4*>(src);
    ushort4 o;
    o.x = f32_to_bf16(v.x); o.y = f32_to_bf16(v.y);
    o.z = f32_to_bf16(v.z); o.w = f32_to_bf16(v.w);
    *reinterpret_cast<ushort4*>(wbf + i) = o;
  } else {
    const int i = (bid - 4608) * 1024 + tid * 4;  // i = n*256 + h
    const int n = i >> 8;
    const int h = i & 255;
    ushort4 o;
    o.x = f32_to_bf16(U[(size_t)(h + 0) * 2048 + n]);
    o.y = f32_to_bf16(U[(size_t)(h + 1) * 2048 + n]);
    o.z = f32_to_bf16(U[(size_t)(h + 2) * 2048 + n]);
    o.w = f32_to_bf16(U[(size_t)(h + 3) * 2048 + n]);
    *reinterpret_cast<ushort4*>(Ut + i) = o;
  }
}

// ---------------------------------------------------------------------------
extern "C" void kernel_launch(void* const* d_in, const int* in_sizes, int n_in,
                              void* d_out, int out_size, void* d_ws, size_t ws_size,
                              hipStream_t stream)
{
  const float* seq = (const float*)d_in[0];
  const float* U   = (const float*)d_in[1];
  const float* Ww  = (const float*)d_in[2];
  const float* Wb  = (const float*)d_in[3];
  const float* sw  = (const float*)d_in[4];
  const float* sb  = (const float*)d_in[5];
  const float* ew  = (const float*)d_in[6];
  const float* eb  = (const float*)d_in[7];
  float* out = (float*)d_out;

  u16* Xbf   = (u16*)d_ws;                 // 4194304
  u16* wbf   = Xbf  + 4194304;             // 524288  [512][1024]
  u16* Utbf  = wbf  + 524288;              // 524288  [2048][256]
  u16* Hboth = Utbf + 524288;              // 2097152 [4096][512]
  u16* Tbf   = Hboth + 2097152;            // 8388608 [4096][2048]
  float* linS = (float*)(Tbf + 8388608);   // 32768
  float* linE = linS + 32768;              // 32768

  prep_kernel<<<5120, BDIM, 0, stream>>>(seq, sw, ew, U, Xbf, wbf, Utbf);

  // K1: Hboth = X @ [sw;ew]^T + [sb;eb]  (64x64 tiles, 512 blocks)
  k1<<<dim3(8, 64, 1), BDIM, 0, stream>>>(Xbf, wbf, Hboth, sb, eb);

  // K2 (T = Hs @ Ut^T) + lin, fused into one launch
  k2lin<<<640, BDIM, 0, stream>>>(Hboth, Utbf, Tbf, Ww, Wb, linS, linE);

  // K3: out[b] = T[b] @ He[b]^T + lin  (128^2, BK=64, 4 blocks/CU)
  gemm128_biaff<<<dim3(8, 64, 4), BDIM, 0, stream>>>(
      Tbf, Hboth + 256, out, linS, linE);
}

// Round 9
// 82.203 us; speedup vs baseline: 1.5048x; 1.0364x over previous
//
#include <hip/hip_runtime.h>
#include <stdint.h>

// BiaffineSpanHead: B=4, S=1024, IN=1024, H=256, C=8
// out[b,s,e,c] = sum_{h,g} Hs[b,s,h] U[h,c,g] He[b,e,g] + linS[b,s,c] + linE[b,e,c] + Wb[c]
//
// R9: 3 launches. prep folded away:
//   k1p  : blocks 0..511  = K1 64x64 GEMM with f32->bf16 reg-staged A/B
//          (reads seq/sw/ew f32 directly; no Xbf/wbf pass);
//          blocks 512..1023 = Ut transpose-cast (k2 input).
//   k2lin: K2 (128^2, BK=64, swizzled staging -- conflict-free) + lin blocks.
//   K3   : gemm128_biaff unchanged (R6/R8-proven, ~write-bound).

#define BDIM 256

typedef float f32x4 __attribute__((ext_vector_type(4)));
typedef __bf16 bf16x8 __attribute__((ext_vector_type(8)));
typedef unsigned int u32;
typedef unsigned short u16;
typedef const __attribute__((address_space(1))) u32* gas_ptr;
typedef __attribute__((address_space(3))) u32* las_ptr;

static __device__ __forceinline__ void load_lds16(const void* g, void* l) {
  __builtin_amdgcn_global_load_lds((gas_ptr)g, (las_ptr)l, 16, 0, 0);
}

static __device__ __forceinline__ u16 f32_to_bf16(float f) {
  union { float f; u32 u; } v; v.f = f;
  u32 r = v.u + 0x7FFFu + ((v.u >> 16) & 1u);
  return (u16)(r >> 16);
}
static __device__ __forceinline__ u32 pack_bf16(float lo, float hi) {
  return (u32)f32_to_bf16(lo) | ((u32)f32_to_bf16(hi) << 16);
}
static __device__ __forceinline__ float bf16lo_to_f32(u32 u) {
  union { u32 u; float f; } v; v.u = u << 16;
  return v.f;
}
static __device__ __forceinline__ float bf16hi_to_f32(u32 u) {
  union { u32 u; float f; } v; v.u = u & 0xFFFF0000u;
  return v.f;
}

// stage a 32-row x 64-col bf16 stripe via global_load_lds; LDS slot sl of row
// r holds k-group sl ^ (r&7) (T2 swizzle via pre-swizzled source).
static __device__ __forceinline__ void stage32(u16* lds, int dst, const u16* src,
                                               int srow, int ld, int kcol, int tid) {
  const int r = tid >> 3;        // 0..31
  const int sl = tid & 7;
  load_lds16(src + (size_t)(srow + r) * ld + kcol + ((sl ^ (r & 7)) << 3),
             &lds[dst + tid * 8]);
}

// same stripe+layout, but source is f32: reg-stage (load f32x8, cvt, one 16B
// ds_write). Write side addr = dst + tid*8 (linear), source k-group sl^(r&7)
// -- bit-identical LDS image to stage32.
static __device__ __forceinline__ void stage32_f32(u16* lds, int dst, const float* src,
                                                   int srow, int ld, int kcol, int tid) {
  const int r = tid >> 3;
  const int sl = tid & 7;
  const float* p = src + (size_t)(srow + r) * ld + kcol + ((sl ^ (r & 7)) << 3);
  const float4 v0 = *reinterpret_cast<const float4*>(p);
  const float4 v1 = *reinterpret_cast<const float4*>(p + 4);
  uint4 w;
  w.x = pack_bf16(v0.x, v0.y);
  w.y = pack_bf16(v0.z, v0.w);
  w.z = pack_bf16(v1.x, v1.y);
  w.w = pack_bf16(v1.z, v1.w);
  *reinterpret_cast<uint4*>(&lds[dst + tid * 8]) = w;
}

// read an 8-elem bf16 fragment from a swizzled 64-col row
static __device__ __forceinline__ bf16x8 rd64(const u16* lds, int base, int row, int kslot) {
  return *reinterpret_cast<const bf16x8*>(&lds[base + row * 64 + ((kslot ^ (row & 7)) << 3)]);
}

// ---------------------------------------------------------------------------
// k1p: blocks <512: Hboth = X @ [sw;ew]^T + bias, 64x64 tile, BK=64,
//      A/B reg-staged f32->bf16 (no prep pass). blocks >=512: Ut cast.
// ---------------------------------------------------------------------------
__global__ __launch_bounds__(BDIM, 4)
void k1p(const float* __restrict__ seq,   // [4096][1024]
         const float* __restrict__ sw,    // [256][1024]
         const float* __restrict__ ew,    // [256][1024]
         const float* __restrict__ U,     // [256][2048]
         const float* __restrict__ sb,
         const float* __restrict__ eb,
         u16* __restrict__ Hboth,         // [4096][512]
         u16* __restrict__ Ut)            // [2048][256]
{
  const int tid = threadIdx.x;
  const int bid = blockIdx.x;

  if (bid >= 512) {
    // ---- Ut transpose-cast: Ut[(c,g)][h] = U[h][(c,g)] ----
    const int i = (bid - 512) * 1024 + tid * 4;   // i = n*256 + h
    const int n = i >> 8;
    const int h = i & 255;
    ushort4 o;
    o.x = f32_to_bf16(U[(size_t)(h + 0) * 2048 + n]);
    o.y = f32_to_bf16(U[(size_t)(h + 1) * 2048 + n]);
    o.z = f32_to_bf16(U[(size_t)(h + 2) * 2048 + n]);
    o.w = f32_to_bf16(U[(size_t)(h + 3) * 2048 + n]);
    *reinterpret_cast<ushort4*>(Ut + i) = o;
    return;
  }

  __shared__ u16 lds[2 * 4096];   // A [64][64] @0, B [64][64] @4096

  const int lane = tid & 63;
  const int wv   = tid >> 6;     // 0..3
  const int wr   = wv >> 1;      // 0..1 (32-row half)
  const int wq   = wv & 1;       // 0..1 (32-col half)
  const int rA   = lane & 15;
  const int kq   = lane >> 4;    // 0..3

  int id = bid;                                     // 0..511
  id = (id & 7) * 64 + (id >> 3);                   // bijective XCD swizzle
  const int n0 = (id & 7) * 64;
  const int m0 = (id >> 3) * 64;

  const float* wsrc = (n0 < 256) ? (sw + (size_t)n0 * 1024)
                                 : (ew + (size_t)(n0 - 256) * 1024);

  f32x4 acc[2][2];
#pragma unroll
  for (int i = 0; i < 2; ++i)
#pragma unroll
    for (int j = 0; j < 2; ++j) acc[i][j] = (f32x4)0.f;

#pragma unroll 1
  for (int kt = 0; kt < 1024; kt += 64) {
    stage32_f32(lds, 0,           seq,  m0,      1024, kt, tid);
    stage32_f32(lds, 2048,        seq,  m0 + 32, 1024, kt, tid);
    stage32_f32(lds, 4096,        wsrc, 0,       1024, kt, tid);
    stage32_f32(lds, 4096 + 2048, wsrc, 32,      1024, kt, tid);
    __syncthreads();

    bf16x8 aF[2][2], bF[2][2];
#pragma unroll
    for (int mi = 0; mi < 2; ++mi)
#pragma unroll
      for (int ks = 0; ks < 2; ++ks)
        aF[mi][ks] = rd64(lds, 0, wr * 32 + mi * 16 + rA, (ks << 2) | kq);
#pragma unroll
    for (int ni = 0; ni < 2; ++ni)
#pragma unroll
      for (int ks = 0; ks < 2; ++ks)
        bF[ni][ks] = rd64(lds, 4096, wq * 32 + ni * 16 + rA, (ks << 2) | kq);
#pragma unroll
    for (int mi = 0; mi < 2; ++mi)
#pragma unroll
      for (int ni = 0; ni < 2; ++ni)
#pragma unroll
        for (int ks = 0; ks < 2; ++ks)
          acc[mi][ni] = __builtin_amdgcn_mfma_f32_16x16x32_bf16(
              aF[mi][ks], bF[ni][ks], acc[mi][ni], 0, 0, 0);
    __syncthreads();
  }

  // epilogue: C/D col=lane&15, row=kq*4+r
#pragma unroll
  for (int mi = 0; mi < 2; ++mi) {
#pragma unroll
    for (int ni = 0; ni < 2; ++ni) {
      const int n = n0 + wq * 32 + ni * 16 + rA;
      const float bn = (n < 256) ? sb[n] : eb[n - 256];
      const int mr = m0 + wr * 32 + mi * 16 + kq * 4;
#pragma unroll
      for (int r = 0; r < 4; ++r)
        Hboth[(size_t)(mr + r) * 512 + n] = f32_to_bf16(acc[mi][ni][r] + bn);
    }
  }
}

// ---------------------------------------------------------------------------
// k2lin: blocks 0..511 = K2 (T = Hs @ Ut^T, 128^2 tile, BK=64, swizzled --
// conflict-free ds_reads); blocks 512..639 = lin.
// ---------------------------------------------------------------------------
__global__ __launch_bounds__(BDIM, 2)
void k2lin(const u16* __restrict__ Hboth,
           const u16* __restrict__ Utbf,
           u16* __restrict__ Tbf,
           const float* __restrict__ Ww,
           const float* __restrict__ Wb,
           float* __restrict__ linS,
           float* __restrict__ linE)
{
  const int bid = blockIdx.x;
  const int tid = threadIdx.x;

  if (bid >= 512) {
    const int idx = (bid - 512) * BDIM + tid;   // 0..32767
    const int m = idx >> 3;
    const int c = idx & 7;
    const uint4* hs4 = reinterpret_cast<const uint4*>(Hboth + (size_t)m * 512);
    const uint4* he4 = reinterpret_cast<const uint4*>(Hboth + (size_t)m * 512 + 256);
    const float* wsp = Ww + c * 512;
    const float* wep = wsp + 256;
    float s1 = 0.f, s2 = 0.f;
#pragma unroll 4
    for (int t = 0; t < 32; ++t) {
      const uint4 a = hs4[t];
      const uint4 b = he4[t];
      const u32 aw[4] = {a.x, a.y, a.z, a.w};
      const u32 bw[4] = {b.x, b.y, b.z, b.w};
#pragma unroll
      for (int q = 0; q < 4; ++q) {
        const int h = t * 8 + q * 2;
        s1 += bf16lo_to_f32(aw[q]) * wsp[h] + bf16hi_to_f32(aw[q]) * wsp[h + 1];
        s2 += bf16lo_to_f32(bw[q]) * wep[h] + bf16hi_to_f32(bw[q]) * wep[h + 1];
      }
    }
    linS[idx] = s1;
    linE[idx] = s2 + Wb[c];
    return;
  }

  __shared__ u16 lds[2 * 8192];   // A [128][64] @0, B [128][64] @8192

  int id = bid;
  id = (id & 7) * 64 + (id >> 3);
  const int n0 = (id & 15) * 128;
  const int m0 = (id >> 4) * 128;

  const int lane = tid & 63;
  const int wv   = tid >> 6;
  const int wr   = wv >> 1;
  const int wc   = wv & 1;
  const int rA   = lane & 15;
  const int kq   = lane >> 4;

  f32x4 acc[4][4];
#pragma unroll
  for (int i = 0; i < 4; ++i)
#pragma unroll
    for (int j = 0; j < 4; ++j) acc[i][j] = (f32x4)0.f;

#pragma unroll 1
  for (int kt = 0; kt < 256; kt += 64) {
#pragma unroll
    for (int h = 0; h < 4; ++h)
      stage32(lds, h * 2048, Hboth, m0 + h * 32, 512, kt, tid);
#pragma unroll
    for (int h = 0; h < 4; ++h)
      stage32(lds, 8192 + h * 2048, Utbf, n0 + h * 32, 256, kt, tid);
    __syncthreads();

    bf16x8 aF[4][2], bF[4][2];
#pragma unroll
    for (int mi = 0; mi < 4; ++mi)
#pragma unroll
      for (int ks = 0; ks < 2; ++ks)
        aF[mi][ks] = rd64(lds, 0, wr * 64 + mi * 16 + rA, (ks << 2) | kq);
#pragma unroll
    for (int ni = 0; ni < 4; ++ni)
#pragma unroll
      for (int ks = 0; ks < 2; ++ks)
        bF[ni][ks] = rd64(lds, 8192, wc * 64 + ni * 16 + rA, (ks << 2) | kq);
#pragma unroll
    for (int mi = 0; mi < 4; ++mi)
#pragma unroll
      for (int ni = 0; ni < 4; ++ni)
#pragma unroll
        for (int ks = 0; ks < 2; ++ks)
          acc[mi][ni] = __builtin_amdgcn_mfma_f32_16x16x32_bf16(
              aF[mi][ks], bF[ni][ks], acc[mi][ni], 0, 0, 0);
    __syncthreads();
  }

#pragma unroll
  for (int mi = 0; mi < 4; ++mi) {
#pragma unroll
    for (int ni = 0; ni < 4; ++ni) {
      const int mBase = m0 + wr * 64 + mi * 16 + kq * 4;
      const int n = n0 + wc * 64 + ni * 16 + rA;
#pragma unroll
      for (int r = 0; r < 4; ++r)
        Tbf[(size_t)(mBase + r) * 2048 + n] = f32_to_bf16(acc[mi][ni][r]);
    }
  }
}

// ---------------------------------------------------------------------------
// K3: 128x128 tile, BK=64, 4 waves, single-buffer 2-phase (R6/R8-proven).
// ---------------------------------------------------------------------------
__global__ __launch_bounds__(BDIM, 4)
void gemm128_biaff(const u16* __restrict__ Tall,
                   const u16* __restrict__ Bg,
                   float* __restrict__ Out,
                   const float* __restrict__ linSall,
                   const float* __restrict__ linEall)
{
  __shared__ u16 lds[2 * 8192];    // lsA at 0, lsB at 8192 (u16 units)

  const int tid  = threadIdx.x;
  const int lane = tid & 63;
  const int wv   = tid >> 6;       // 0..3
  const int wr   = wv >> 1;        // 0..1
  const int wc   = wv & 1;         // 0..1
  const int rA   = lane & 15;
  const int kq   = lane >> 4;      // 0..3
  const int z    = blockIdx.z;

  int id = blockIdx.y * gridDim.x + blockIdx.x;
  id = (id & 7) * 64 + (id >> 3);
  const int n0 = (id & 7) * 128;
  const int m0 = (id >> 3) * 128;

  const u16* Ag  = Tall + (size_t)z * (8192 * 256);
  const u16* Bgz = Bg   + (size_t)z * (1024 * 512);

  f32x4 acc[4][4];
#pragma unroll
  for (int i = 0; i < 4; ++i)
#pragma unroll
    for (int j = 0; j < 4; ++j) acc[i][j] = (f32x4)0.f;

#pragma unroll 1
  for (int kt = 0; kt < 256; kt += 64) {
#pragma unroll
    for (int h = 0; h < 4; ++h)
      stage32(lds, h * 2048, Ag, m0 + h * 32, 256, kt, tid);
#pragma unroll
    for (int h = 0; h < 4; ++h)
      stage32(lds, 8192 + h * 2048, Bgz, n0 + h * 32, 512, kt, tid);
    __syncthreads();

    bf16x8 aF[4][2], bF[4][2];
#pragma unroll
    for (int mi = 0; mi < 4; ++mi)
#pragma unroll
      for (int ks = 0; ks < 2; ++ks)
        aF[mi][ks] = rd64(lds, 0, wr * 64 + mi * 16 + rA, (ks << 2) | kq);
#pragma unroll
    for (int ni = 0; ni < 4; ++ni)
#pragma unroll
      for (int ks = 0; ks < 2; ++ks)
        bF[ni][ks] = rd64(lds, 8192, wc * 64 + ni * 16 + rA, (ks << 2) | kq);
#pragma unroll
    for (int mi = 0; mi < 4; ++mi)
#pragma unroll
      for (int ni = 0; ni < 4; ++ni)
#pragma unroll
        for (int ks = 0; ks < 2; ++ks)
          acc[mi][ni] = __builtin_amdgcn_mfma_f32_16x16x32_bf16(
              aF[mi][ks], bF[ni][ks], acc[mi][ni], 0, 0, 0);
    __syncthreads();
  }

  float* OutZ = Out + (size_t)z * 8388608;
  const float* lS = linSall + (size_t)z * 8192;
  const float* lE = linEall + (size_t)z * 8192;
#pragma unroll
  for (int mi = 0; mi < 4; ++mi) {
#pragma unroll
    for (int ni = 0; ni < 4; ++ni) {
      const int mBase = m0 + wr * 64 + mi * 16 + kq * 4;   // = s*8 + c0
      const int e = n0 + wc * 64 + ni * 16 + rA;
      const int s = mBase >> 3;
      const int c0 = mBase & 7;
      const float4 ls4 = *reinterpret_cast<const float4*>(lS + mBase);
      const float4 le4 = *reinterpret_cast<const float4*>(lE + (e << 3) + c0);
      float4 o;
      o.x = acc[mi][ni][0] + ls4.x + le4.x;
      o.y = acc[mi][ni][1] + ls4.y + le4.y;
      o.z = acc[mi][ni][2] + ls4.z + le4.z;
      o.w = acc[mi][ni][3] + ls4.w + le4.w;
      *reinterpret_cast<float4*>(OutZ + ((size_t)s << 13) + ((size_t)e << 3) + c0) = o;
    }
  }
}

// ---------------------------------------------------------------------------
extern "C" void kernel_launch(void* const* d_in, const int* in_sizes, int n_in,
                              void* d_out, int out_size, void* d_ws, size_t ws_size,
                              hipStream_t stream)
{
  const float* seq = (const float*)d_in[0];
  const float* U   = (const float*)d_in[1];
  const float* Ww  = (const float*)d_in[2];
  const float* Wb  = (const float*)d_in[3];
  const float* sw  = (const float*)d_in[4];
  const float* sb  = (const float*)d_in[5];
  const float* ew  = (const float*)d_in[6];
  const float* eb  = (const float*)d_in[7];
  float* out = (float*)d_out;

  u16* Utbf  = (u16*)d_ws;                 // 524288  [2048][256]
  u16* Hboth = Utbf + 524288;              // 2097152 [4096][512]
  u16* Tbf   = Hboth + 2097152;            // 8388608 [4096][2048]
  float* linS = (float*)(Tbf + 8388608);   // 32768
  float* linE = linS + 32768;              // 32768

  // K1 + Ut-cast (prep eliminated)
  k1p<<<1024, BDIM, 0, stream>>>(seq, sw, ew, U, sb, eb, Hboth, Utbf);

  // K2 (swizzled BK=64) + lin
  k2lin<<<640, BDIM, 0, stream>>>(Hboth, Utbf, Tbf, Ww, Wb, linS, linE);

  // K3: out[b] = T[b] @ He[b]^T + lin  (128^2, BK=64, 4 blocks/CU)
  gemm128_biaff<<<dim3(8, 64, 4), BDIM, 0, stream>>>(
      Tbf, Hboth + 256, out, linS, linE);
}

// Round 10
// 80.766 us; speedup vs baseline: 1.5316x; 1.0178x over previous
//
#include <hip/hip_runtime.h>
#include <stdint.h>

// BiaffineSpanHead: B=4, S=1024, IN=1024, H=256, C=8
// out[b,s,e,c] = sum_{h,g} Hs[b,s,h] U[h,c,g] He[b,e,g] + linS[b,s,c] + linE[b,e,c] + Wb[c]
//
// R10: single-variable experiment. k1p, k2lin identical to R9. K3 rewritten:
// 128x128 tile, BK=64, DOUBLE-buffered staging (64KB LDS, 2 blocks/CU) with
// counted vmcnt(8) + raw s_barrier (no full drain mid-loop).

#define BDIM 256

typedef float f32x4 __attribute__((ext_vector_type(4)));
typedef __bf16 bf16x8 __attribute__((ext_vector_type(8)));
typedef unsigned int u32;
typedef unsigned short u16;
typedef const __attribute__((address_space(1))) u32* gas_ptr;
typedef __attribute__((address_space(3))) u32* las_ptr;

static __device__ __forceinline__ void load_lds16(const void* g, void* l) {
  __builtin_amdgcn_global_load_lds((gas_ptr)g, (las_ptr)l, 16, 0, 0);
}

static __device__ __forceinline__ u16 f32_to_bf16(float f) {
  union { float f; u32 u; } v; v.f = f;
  u32 r = v.u + 0x7FFFu + ((v.u >> 16) & 1u);
  return (u16)(r >> 16);
}
static __device__ __forceinline__ u32 pack_bf16(float lo, float hi) {
  return (u32)f32_to_bf16(lo) | ((u32)f32_to_bf16(hi) << 16);
}
static __device__ __forceinline__ float bf16lo_to_f32(u32 u) {
  union { u32 u; float f; } v; v.u = u << 16;
  return v.f;
}
static __device__ __forceinline__ float bf16hi_to_f32(u32 u) {
  union { u32 u; float f; } v; v.u = u & 0xFFFF0000u;
  return v.f;
}

// stage a 32-row x 64-col bf16 stripe via global_load_lds; LDS slot sl of row
// r holds k-group sl ^ (r&7) (T2 swizzle via pre-swizzled source).
static __device__ __forceinline__ void stage32(u16* lds, int dst, const u16* src,
                                               int srow, int ld, int kcol, int tid) {
  const int r = tid >> 3;        // 0..31
  const int sl = tid & 7;
  load_lds16(src + (size_t)(srow + r) * ld + kcol + ((sl ^ (r & 7)) << 3),
             &lds[dst + tid * 8]);
}

// same stripe+layout, but source is f32: reg-stage (load f32x8, cvt, one 16B
// ds_write). Bit-identical LDS image to stage32.
static __device__ __forceinline__ void stage32_f32(u16* lds, int dst, const float* src,
                                                   int srow, int ld, int kcol, int tid) {
  const int r = tid >> 3;
  const int sl = tid & 7;
  const float* p = src + (size_t)(srow + r) * ld + kcol + ((sl ^ (r & 7)) << 3);
  const float4 v0 = *reinterpret_cast<const float4*>(p);
  const float4 v1 = *reinterpret_cast<const float4*>(p + 4);
  uint4 w;
  w.x = pack_bf16(v0.x, v0.y);
  w.y = pack_bf16(v0.z, v0.w);
  w.z = pack_bf16(v1.x, v1.y);
  w.w = pack_bf16(v1.z, v1.w);
  *reinterpret_cast<uint4*>(&lds[dst + tid * 8]) = w;
}

// read an 8-elem bf16 fragment from a swizzled 64-col row
static __device__ __forceinline__ bf16x8 rd64(const u16* lds, int base, int row, int kslot) {
  return *reinterpret_cast<const bf16x8*>(&lds[base + row * 64 + ((kslot ^ (row & 7)) << 3)]);
}

// ---------------------------------------------------------------------------
// k1p: blocks <512: Hboth = X @ [sw;ew]^T + bias, 64x64 tile, BK=64,
//      A/B reg-staged f32->bf16. blocks >=512: Ut cast.  (R9-proven, verbatim)
// ---------------------------------------------------------------------------
__global__ __launch_bounds__(BDIM, 4)
void k1p(const float* __restrict__ seq,   // [4096][1024]
         const float* __restrict__ sw,    // [256][1024]
         const float* __restrict__ ew,    // [256][1024]
         const float* __restrict__ U,     // [256][2048]
         const float* __restrict__ sb,
         const float* __restrict__ eb,
         u16* __restrict__ Hboth,         // [4096][512]
         u16* __restrict__ Ut)            // [2048][256]
{
  const int tid = threadIdx.x;
  const int bid = blockIdx.x;

  if (bid >= 512) {
    const int i = (bid - 512) * 1024 + tid * 4;   // i = n*256 + h
    const int n = i >> 8;
    const int h = i & 255;
    ushort4 o;
    o.x = f32_to_bf16(U[(size_t)(h + 0) * 2048 + n]);
    o.y = f32_to_bf16(U[(size_t)(h + 1) * 2048 + n]);
    o.z = f32_to_bf16(U[(size_t)(h + 2) * 2048 + n]);
    o.w = f32_to_bf16(U[(size_t)(h + 3) * 2048 + n]);
    *reinterpret_cast<ushort4*>(Ut + i) = o;
    return;
  }

  __shared__ u16 lds[2 * 4096];   // A [64][64] @0, B [64][64] @4096

  const int lane = tid & 63;
  const int wv   = tid >> 6;     // 0..3
  const int wr   = wv >> 1;      // 0..1 (32-row half)
  const int wq   = wv & 1;       // 0..1 (32-col half)
  const int rA   = lane & 15;
  const int kq   = lane >> 4;    // 0..3

  int id = bid;                                     // 0..511
  id = (id & 7) * 64 + (id >> 3);                   // bijective XCD swizzle
  const int n0 = (id & 7) * 64;
  const int m0 = (id >> 3) * 64;

  const float* wsrc = (n0 < 256) ? (sw + (size_t)n0 * 1024)
                                 : (ew + (size_t)(n0 - 256) * 1024);

  f32x4 acc[2][2];
#pragma unroll
  for (int i = 0; i < 2; ++i)
#pragma unroll
    for (int j = 0; j < 2; ++j) acc[i][j] = (f32x4)0.f;

#pragma unroll 1
  for (int kt = 0; kt < 1024; kt += 64) {
    stage32_f32(lds, 0,           seq,  m0,      1024, kt, tid);
    stage32_f32(lds, 2048,        seq,  m0 + 32, 1024, kt, tid);
    stage32_f32(lds, 4096,        wsrc, 0,       1024, kt, tid);
    stage32_f32(lds, 4096 + 2048, wsrc, 32,      1024, kt, tid);
    __syncthreads();

    bf16x8 aF[2][2], bF[2][2];
#pragma unroll
    for (int mi = 0; mi < 2; ++mi)
#pragma unroll
      for (int ks = 0; ks < 2; ++ks)
        aF[mi][ks] = rd64(lds, 0, wr * 32 + mi * 16 + rA, (ks << 2) | kq);
#pragma unroll
    for (int ni = 0; ni < 2; ++ni)
#pragma unroll
      for (int ks = 0; ks < 2; ++ks)
        bF[ni][ks] = rd64(lds, 4096, wq * 32 + ni * 16 + rA, (ks << 2) | kq);
#pragma unroll
    for (int mi = 0; mi < 2; ++mi)
#pragma unroll
      for (int ni = 0; ni < 2; ++ni)
#pragma unroll
        for (int ks = 0; ks < 2; ++ks)
          acc[mi][ni] = __builtin_amdgcn_mfma_f32_16x16x32_bf16(
              aF[mi][ks], bF[ni][ks], acc[mi][ni], 0, 0, 0);
    __syncthreads();
  }

#pragma unroll
  for (int mi = 0; mi < 2; ++mi) {
#pragma unroll
    for (int ni = 0; ni < 2; ++ni) {
      const int n = n0 + wq * 32 + ni * 16 + rA;
      const float bn = (n < 256) ? sb[n] : eb[n - 256];
      const int mr = m0 + wr * 32 + mi * 16 + kq * 4;
#pragma unroll
      for (int r = 0; r < 4; ++r)
        Hboth[(size_t)(mr + r) * 512 + n] = f32_to_bf16(acc[mi][ni][r] + bn);
    }
  }
}

// ---------------------------------------------------------------------------
// k2lin (R9-proven, verbatim): blocks 0..511 = K2 (128^2, BK=64, swizzled);
// blocks 512..639 = lin.
// ---------------------------------------------------------------------------
__global__ __launch_bounds__(BDIM, 2)
void k2lin(const u16* __restrict__ Hboth,
           const u16* __restrict__ Utbf,
           u16* __restrict__ Tbf,
           const float* __restrict__ Ww,
           const float* __restrict__ Wb,
           float* __restrict__ linS,
           float* __restrict__ linE)
{
  const int bid = blockIdx.x;
  const int tid = threadIdx.x;

  if (bid >= 512) {
    const int idx = (bid - 512) * BDIM + tid;   // 0..32767
    const int m = idx >> 3;
    const int c = idx & 7;
    const uint4* hs4 = reinterpret_cast<const uint4*>(Hboth + (size_t)m * 512);
    const uint4* he4 = reinterpret_cast<const uint4*>(Hboth + (size_t)m * 512 + 256);
    const float* wsp = Ww + c * 512;
    const float* wep = wsp + 256;
    float s1 = 0.f, s2 = 0.f;
#pragma unroll 4
    for (int t = 0; t < 32; ++t) {
      const uint4 a = hs4[t];
      const uint4 b = he4[t];
      const u32 aw[4] = {a.x, a.y, a.z, a.w};
      const u32 bw[4] = {b.x, b.y, b.z, b.w};
#pragma unroll
      for (int q = 0; q < 4; ++q) {
        const int h = t * 8 + q * 2;
        s1 += bf16lo_to_f32(aw[q]) * wsp[h] + bf16hi_to_f32(aw[q]) * wsp[h + 1];
        s2 += bf16lo_to_f32(bw[q]) * wep[h] + bf16hi_to_f32(bw[q]) * wep[h + 1];
      }
    }
    linS[idx] = s1;
    linE[idx] = s2 + Wb[c];
    return;
  }

  __shared__ u16 lds[2 * 8192];   // A [128][64] @0, B [128][64] @8192

  int id = bid;
  id = (id & 7) * 64 + (id >> 3);
  const int n0 = (id & 15) * 128;
  const int m0 = (id >> 4) * 128;

  const int lane = tid & 63;
  const int wv   = tid >> 6;
  const int wr   = wv >> 1;
  const int wc   = wv & 1;
  const int rA   = lane & 15;
  const int kq   = lane >> 4;

  f32x4 acc[4][4];
#pragma unroll
  for (int i = 0; i < 4; ++i)
#pragma unroll
    for (int j = 0; j < 4; ++j) acc[i][j] = (f32x4)0.f;

#pragma unroll 1
  for (int kt = 0; kt < 256; kt += 64) {
#pragma unroll
    for (int h = 0; h < 4; ++h)
      stage32(lds, h * 2048, Hboth, m0 + h * 32, 512, kt, tid);
#pragma unroll
    for (int h = 0; h < 4; ++h)
      stage32(lds, 8192 + h * 2048, Utbf, n0 + h * 32, 256, kt, tid);
    __syncthreads();

    bf16x8 aF[4][2], bF[4][2];
#pragma unroll
    for (int mi = 0; mi < 4; ++mi)
#pragma unroll
      for (int ks = 0; ks < 2; ++ks)
        aF[mi][ks] = rd64(lds, 0, wr * 64 + mi * 16 + rA, (ks << 2) | kq);
#pragma unroll
    for (int ni = 0; ni < 4; ++ni)
#pragma unroll
      for (int ks = 0; ks < 2; ++ks)
        bF[ni][ks] = rd64(lds, 8192, wc * 64 + ni * 16 + rA, (ks << 2) | kq);
#pragma unroll
    for (int mi = 0; mi < 4; ++mi)
#pragma unroll
      for (int ni = 0; ni < 4; ++ni)
#pragma unroll
        for (int ks = 0; ks < 2; ++ks)
          acc[mi][ni] = __builtin_amdgcn_mfma_f32_16x16x32_bf16(
              aF[mi][ks], bF[ni][ks], acc[mi][ni], 0, 0, 0);
    __syncthreads();
  }

#pragma unroll
  for (int mi = 0; mi < 4; ++mi) {
#pragma unroll
    for (int ni = 0; ni < 4; ++ni) {
      const int mBase = m0 + wr * 64 + mi * 16 + kq * 4;
      const int n = n0 + wc * 64 + ni * 16 + rA;
#pragma unroll
      for (int r = 0; r < 4; ++r)
        Tbf[(size_t)(mBase + r) * 2048 + n] = f32_to_bf16(acc[mi][ni][r]);
    }
  }
}

// ---------------------------------------------------------------------------
// K3: 128x128 tile, BK=64, DOUBLE-buffered (64KB LDS, 2 blocks/CU), counted
// vmcnt(8) + raw s_barrier -- next tile's loads stay in flight across compute.
// ---------------------------------------------------------------------------
#define K3STAGE(buf, t) do {                                                   \
    _Pragma("unroll")                                                          \
    for (int h = 0; h < 4; ++h)                                                \
      stage32(lds, (buf) * 16384 + h * 2048, Ag, m0 + h * 32, 256, (t) * 64, tid); \
    _Pragma("unroll")                                                          \
    for (int h = 0; h < 4; ++h)                                                \
      stage32(lds, (buf) * 16384 + 8192 + h * 2048, Bgz, n0 + h * 32, 512, (t) * 64, tid); \
  } while (0)

__global__ __launch_bounds__(BDIM, 2)
void gemm128_biaff(const u16* __restrict__ Tall,
                   const u16* __restrict__ Bg,
                   float* __restrict__ Out,
                   const float* __restrict__ linSall,
                   const float* __restrict__ linEall)
{
  __shared__ u16 lds[4 * 8192];    // bufA0 @0, bufB0 @8192, bufA1 @16384, bufB1 @24576

  const int tid  = threadIdx.x;
  const int lane = tid & 63;
  const int wv   = tid >> 6;       // 0..3
  const int wr   = wv >> 1;        // 0..1
  const int wc   = wv & 1;         // 0..1
  const int rA   = lane & 15;
  const int kq   = lane >> 4;      // 0..3
  const int z    = blockIdx.z;

  int id = blockIdx.y * gridDim.x + blockIdx.x;
  id = (id & 7) * 64 + (id >> 3);
  const int n0 = (id & 7) * 128;
  const int m0 = (id >> 3) * 128;

  const u16* Ag  = Tall + (size_t)z * (8192 * 256);
  const u16* Bgz = Bg   + (size_t)z * (1024 * 512);

  f32x4 acc[4][4];
#pragma unroll
  for (int i = 0; i < 4; ++i)
#pragma unroll
    for (int j = 0; j < 4; ++j) acc[i][j] = (f32x4)0.f;

  // hoist linS loads (independent of the K-loop)
  const float* lS = linSall + (size_t)z * 8192;
  float4 ls4[4];
#pragma unroll
  for (int mi = 0; mi < 4; ++mi)
    ls4[mi] = *reinterpret_cast<const float4*>(lS + m0 + wr * 64 + mi * 16 + kq * 4);

  // prologue: tile 0 -> buf 0
  K3STAGE(0, 0);

#pragma unroll
  for (int t = 0; t < 4; ++t) {
    const int cur = t & 1;
    if (t < 3) {
      K3STAGE(cur ^ 1, t + 1);                       // issue next-tile loads
      asm volatile("s_waitcnt vmcnt(8)" ::: "memory"); // cur's 8 landed; next's in flight
    } else {
      asm volatile("s_waitcnt vmcnt(0)" ::: "memory");
    }
    __builtin_amdgcn_sched_barrier(0);
    __builtin_amdgcn_s_barrier();

    bf16x8 aF[4][2], bF[4][2];
#pragma unroll
    for (int mi = 0; mi < 4; ++mi)
#pragma unroll
      for (int ks = 0; ks < 2; ++ks)
        aF[mi][ks] = rd64(lds, cur * 16384, wr * 64 + mi * 16 + rA, (ks << 2) | kq);
#pragma unroll
    for (int ni = 0; ni < 4; ++ni)
#pragma unroll
      for (int ks = 0; ks < 2; ++ks)
        bF[ni][ks] = rd64(lds, cur * 16384 + 8192, wc * 64 + ni * 16 + rA, (ks << 2) | kq);
#pragma unroll
    for (int mi = 0; mi < 4; ++mi)
#pragma unroll
      for (int ni = 0; ni < 4; ++ni)
#pragma unroll
        for (int ks = 0; ks < 2; ++ks)
          acc[mi][ni] = __builtin_amdgcn_mfma_f32_16x16x32_bf16(
              aF[mi][ks], bF[ni][ks], acc[mi][ni], 0, 0, 0);

    __builtin_amdgcn_sched_barrier(0);
    __builtin_amdgcn_s_barrier();   // WAR: all waves done reading buf cur
  }

  float* OutZ = Out + (size_t)z * 8388608;
  const float* lE = linEall + (size_t)z * 8192;
#pragma unroll
  for (int mi = 0; mi < 4; ++mi) {
#pragma unroll
    for (int ni = 0; ni < 4; ++ni) {
      const int mBase = m0 + wr * 64 + mi * 16 + kq * 4;   // = s*8 + c0
      const int e = n0 + wc * 64 + ni * 16 + rA;
      const int s = mBase >> 3;
      const int c0 = mBase & 7;
      const float4 le4 = *reinterpret_cast<const float4*>(lE + (e << 3) + c0);
      float4 o;
      o.x = acc[mi][ni][0] + ls4[mi].x + le4.x;
      o.y = acc[mi][ni][1] + ls4[mi].y + le4.y;
      o.z = acc[mi][ni][2] + ls4[mi].z + le4.z;
      o.w = acc[mi][ni][3] + ls4[mi].w + le4.w;
      *reinterpret_cast<float4*>(OutZ + ((size_t)s << 13) + ((size_t)e << 3) + c0) = o;
    }
  }
}

// ---------------------------------------------------------------------------
extern "C" void kernel_launch(void* const* d_in, const int* in_sizes, int n_in,
                              void* d_out, int out_size, void* d_ws, size_t ws_size,
                              hipStream_t stream)
{
  const float* seq = (const float*)d_in[0];
  const float* U   = (const float*)d_in[1];
  const float* Ww  = (const float*)d_in[2];
  const float* Wb  = (const float*)d_in[3];
  const float* sw  = (const float*)d_in[4];
  const float* sb  = (const float*)d_in[5];
  const float* ew  = (const float*)d_in[6];
  const float* eb  = (const float*)d_in[7];
  float* out = (float*)d_out;

  u16* Utbf  = (u16*)d_ws;                 // 524288  [2048][256]
  u16* Hboth = Utbf + 524288;              // 2097152 [4096][512]
  u16* Tbf   = Hboth + 2097152;            // 8388608 [4096][2048]
  float* linS = (float*)(Tbf + 8388608);   // 32768
  float* linE = linS + 32768;              // 32768

  // K1 + Ut-cast
  k1p<<<1024, BDIM, 0, stream>>>(seq, sw, ew, U, sb, eb, Hboth, Utbf);

  // K2 (swizzled BK=64) + lin
  k2lin<<<640, BDIM, 0, stream>>>(Hboth, Utbf, Tbf, Ww, Wb, linS, linE);

  // K3: out[b] = T[b] @ He[b]^T + lin  (128^2, BK=64 dbuf, counted vmcnt)
  gemm128_biaff<<<dim3(8, 64, 4), BDIM, 0, stream>>>(
      Tbf, Hboth + 256, out, linS, linE);
}